// Round 5
// baseline (947.911 us; speedup 1.0000x reference)
//
#include <hip/hip_runtime.h>
#include <math.h>

#define NN 50000
#define EE 800000
#define NPAIR 200000

typedef unsigned short u16;
typedef short short8v __attribute__((ext_vector_type(8)));
typedef float float16v __attribute__((ext_vector_type(16)));

__device__ __forceinline__ float leaky(float x){ return x >= 0.f ? x : 0.2f*x; }

// bf16 round-to-nearest-even helpers for the hi/lo split
__device__ __forceinline__ u16 bfhi(float x){
  union{float f; unsigned u;} v; v.f = x;
  unsigned r = (v.u + 0x7FFFu + ((v.u >> 16) & 1u)) >> 16;
  return (u16)r;
}
__device__ __forceinline__ float bf2f(u16 h){
  union{unsigned u; float f;} v; v.u = ((unsigned)h) << 16; return v.f;
}
__device__ __forceinline__ void split2(float x, float y, unsigned &hp, unsigned &lp){
  u16 hx = bfhi(x), hy = bfhi(y);
  u16 lx = bfhi(x - bf2f(hx)), ly = bfhi(y - bf2f(hy));
  hp = (unsigned)hx | ((unsigned)hy << 16);
  lp = (unsigned)lx | ((unsigned)ly << 16);
}
#define MFMA_BF16 __builtin_amdgcn_mfma_f32_32x32x16_bf16

// ---------------- degree / norms / CSR build ----------------

__global__ void degree_kernel(const int* __restrict__ src, const int* __restrict__ dst,
                              int* cnt_out, int* cnt_in){
  int i = blockIdx.x*blockDim.x + threadIdx.x;
  if(i < EE){
    atomicAdd(&cnt_out[src[i]], 1);
    atomicAdd(&cnt_in[dst[i]], 1);
  }
}

__global__ void norm_kernel(const int* __restrict__ cnt_out, const int* __restrict__ cnt_in,
                            float* __restrict__ out_norm, float* __restrict__ in_norm){
  int i = blockIdx.x*blockDim.x + threadIdx.x;
  if(i < NN){
    int o = cnt_out[i]; if(o < 1) o = 1;
    int d = cnt_in[i];  if(d < 1) d = 1;
    out_norm[i] = 1.f/sqrtf((float)o);
    in_norm[i]  = 1.f/sqrtf((float)d);
  }
}

// single-block exclusive scan of cnt_in[NN] -> row_off[NN+1]
__global__ void scan_kernel(const int* __restrict__ cnt, int* __restrict__ row_off){
  const int T = 512;
  __shared__ int sums[T];
  int t = threadIdx.x;
  int chunk = (NN + T - 1)/T;
  int base = t*chunk;
  int hi = base + chunk; if(hi > NN) hi = NN;
  int s = 0;
  for(int i = base; i < hi; i++) s += cnt[i];
  sums[t] = s;
  __syncthreads();
  for(int off = 1; off < T; off <<= 1){
    int add = (t >= off) ? sums[t-off] : 0;
    __syncthreads();
    sums[t] += add;
    __syncthreads();
  }
  int run = sums[t] - s;
  for(int i = base; i < hi; i++){ row_off[i] = run; run += cnt[i]; }
  if(t == T-1) row_off[NN] = EE;
}

// ew2 = w * out_norm[src]: out_norm commutes with @W, folded into edge weight.
__global__ void bucket_kernel(const int* __restrict__ src, const int* __restrict__ dst,
                              const float* __restrict__ w, const float* __restrict__ out_norm,
                              const int* __restrict__ row_off,
                              int* fill, int* __restrict__ es, float* __restrict__ ew){
  int i = blockIdx.x*blockDim.x + threadIdx.x;
  if(i < EE){
    int d = dst[i];
    int s = src[i];
    int p = row_off[d] + atomicAdd(&fill[d], 1);
    es[p] = s;
    ew[p] = w[i] * out_norm[s];
  }
}

// W (K x M fp32, row-major) -> Wt_hi / Wt_lo (M x K bf16), transposed.
__global__ void wsplit_kernel(const float* __restrict__ W, int K, int M,
                              u16* __restrict__ Whi, u16* __restrict__ Wlo){
  int i = blockIdx.x*256 + threadIdx.x;     // i = m*K + k
  if(i < K*M){
    int m = i / K, k = i - m*K;
    float a = W[(size_t)k*M + m];
    u16 h = bfhi(a);
    Whi[i] = h;
    Wlo[i] = bfhi(a - bf2f(h));
  }
}

// P1 (160x80) -> P1t hi/lo [96 cols][160 k] (cols 80..95 zero);
// P2 (80x40)  -> P2t hi/lo [64 cols][80 k]  (cols 40..63 zero).
__global__ void psplit_kernel(const float* __restrict__ P1, const float* __restrict__ P2,
                              u16* __restrict__ P1th, u16* __restrict__ P1tl,
                              u16* __restrict__ P2th, u16* __restrict__ P2tl){
  int i = blockIdx.x*256 + threadIdx.x;
  if(i < 96*160){
    int c = i/160, k = i - c*160;
    float v = (c < 80) ? P1[k*80 + c] : 0.f;
    u16 h = bfhi(v);
    P1th[i] = h; P1tl[i] = bfhi(v - bf2f(h));
  }
  if(i < 64*80){
    int c = i/80, k = i - c*80;
    float v = (c < 40) ? P2[k*40 + c] : 0.f;
    u16 h = bfhi(v);
    P2th[i] = h; P2tl[i] = bfhi(v - bf2f(h));
  }
}

// ---------------- aggregation v5: wave/node, producer-side bf16 split (R14) --
// MODE 0: raw agg -> split hi/lo (feeds GEMM A directly).
// MODE 1: relu(*innorm+bias) -> split hi/lo (h2, feeds GEMM3 A).
// MODE 2: *innorm+bias -> fp32 (h3 final output; predictor gathers fp32).
// Identical arithmetic to splitting inside the GEMM (same values, same split
// points) -> bit-identical results; just moves the split off the GEMM hot loop.
template<int F, int MODE>
__global__ __launch_bounds__(256) void agg_kernel(
    const float* __restrict__ feat, const int* __restrict__ es,
    const float* __restrict__ ew, const int* __restrict__ row_off,
    const float* __restrict__ innorm, const float* __restrict__ bias,
    float* __restrict__ out_f, u16* __restrict__ out_h, u16* __restrict__ out_l){
  constexpr int F4 = F/4;
  int wid = threadIdx.x >> 6, lane = threadIdx.x & 63;
  int v = blockIdx.x*4 + wid;
  if(v >= NN || lane >= F4) return;
  int s = row_off[v], e = row_off[v+1];
  const float4* f4 = (const float4*)feat;
  float4 a0 = {0,0,0,0}, a1 = {0,0,0,0}, a2 = {0,0,0,0}, a3 = {0,0,0,0};
  int j = s;
  for(; j + 7 < e; j += 8){
    int   i0 = es[j],   i1 = es[j+1], i2 = es[j+2], i3 = es[j+3];
    int   i4 = es[j+4], i5 = es[j+5], i6 = es[j+6], i7 = es[j+7];
    float w0 = ew[j],   w1 = ew[j+1], w2 = ew[j+2], w3 = ew[j+3];
    float w4 = ew[j+4], w5 = ew[j+5], w6 = ew[j+6], w7 = ew[j+7];
    float4 r0 = f4[(size_t)i0*F4 + lane];
    float4 r1 = f4[(size_t)i1*F4 + lane];
    float4 r2 = f4[(size_t)i2*F4 + lane];
    float4 r3 = f4[(size_t)i3*F4 + lane];
    float4 r4 = f4[(size_t)i4*F4 + lane];
    float4 r5 = f4[(size_t)i5*F4 + lane];
    float4 r6 = f4[(size_t)i6*F4 + lane];
    float4 r7 = f4[(size_t)i7*F4 + lane];
    a0.x += r0.x*w0; a0.y += r0.y*w0; a0.z += r0.z*w0; a0.w += r0.w*w0;
    a1.x += r1.x*w1; a1.y += r1.y*w1; a1.z += r1.z*w1; a1.w += r1.w*w1;
    a2.x += r2.x*w2; a2.y += r2.y*w2; a2.z += r2.z*w2; a2.w += r2.w*w2;
    a3.x += r3.x*w3; a3.y += r3.y*w3; a3.z += r3.z*w3; a3.w += r3.w*w3;
    a0.x += r4.x*w4; a0.y += r4.y*w4; a0.z += r4.z*w4; a0.w += r4.w*w4;
    a1.x += r5.x*w5; a1.y += r5.y*w5; a1.z += r5.z*w5; a1.w += r5.w*w5;
    a2.x += r6.x*w6; a2.y += r6.y*w6; a2.z += r6.z*w6; a2.w += r6.w*w6;
    a3.x += r7.x*w7; a3.y += r7.y*w7; a3.z += r7.z*w7; a3.w += r7.w*w7;
  }
  for(; j + 3 < e; j += 4){
    int   i0 = es[j],   i1 = es[j+1], i2 = es[j+2], i3 = es[j+3];
    float w0 = ew[j],   w1 = ew[j+1], w2 = ew[j+2], w3 = ew[j+3];
    float4 r0 = f4[(size_t)i0*F4 + lane];
    float4 r1 = f4[(size_t)i1*F4 + lane];
    float4 r2 = f4[(size_t)i2*F4 + lane];
    float4 r3 = f4[(size_t)i3*F4 + lane];
    a0.x += r0.x*w0; a0.y += r0.y*w0; a0.z += r0.z*w0; a0.w += r0.w*w0;
    a1.x += r1.x*w1; a1.y += r1.y*w1; a1.z += r1.z*w1; a1.w += r1.w*w1;
    a2.x += r2.x*w2; a2.y += r2.y*w2; a2.z += r2.z*w2; a2.w += r2.w*w2;
    a3.x += r3.x*w3; a3.y += r3.y*w3; a3.z += r3.z*w3; a3.w += r3.w*w3;
  }
  for(; j < e; j++){
    int idx = es[j]; float wt = ew[j];
    float4 r = f4[(size_t)idx*F4 + lane];
    a0.x += r.x*wt; a0.y += r.y*wt; a0.z += r.z*wt; a0.w += r.w*wt;
  }
  float4 r;
  r.x = (a0.x+a1.x)+(a2.x+a3.x);
  r.y = (a0.y+a1.y)+(a2.y+a3.y);
  r.z = (a0.z+a1.z)+(a2.z+a3.z);
  r.w = (a0.w+a1.w)+(a2.w+a3.w);
  if(MODE >= 1){
    float inm = innorm[v];
    float4 bb = *(const float4*)&bias[lane*4];
    r.x = r.x*inm + bb.x; r.y = r.y*inm + bb.y;
    r.z = r.z*inm + bb.z; r.w = r.w*inm + bb.w;
    if(MODE == 1){
      r.x = fmaxf(r.x, 0.f); r.y = fmaxf(r.y, 0.f);
      r.z = fmaxf(r.z, 0.f); r.w = fmaxf(r.w, 0.f);
    }
  }
  if(MODE == 2){
    ((float4*)(out_f + (size_t)v*F))[lane] = r;
  } else {
    unsigned hp0, lp0, hp1, lp1;
    split2(r.x, r.y, hp0, lp0);
    split2(r.z, r.w, hp1, lp1);
    *(uint2*)&out_h[(size_t)v*F + lane*4] = make_uint2(hp0, hp1);
    *(uint2*)&out_l[(size_t)v*F + lane*4] = make_uint2(lp0, lp1);
  }
}

// ---------------- GEMM v2: MFMA with PRE-SPLIT A (R14) -----------------------
// R14 theory: R9's gemm was VALU-bound — 8 split2/thread/K-step (~110-130 VALU
// instr, ~220-260 cy at wave64) vs 12 MFMA (~96 cy), and the split repeated
// per column-block (L1 x4, L2/L3 x2). A now arrives pre-split from the
// producer (agg epilogue / gemm1 epilogue): staging is pure uint4 loads ->
// LDS, zero split arithmetic in the hot loop.
// OM 0: write fp32 C (feeds the next agg gather).
// OM 1: relu(*innorm+bias) -> split u16 hi/lo (h1, feeds gemm2's A).
template<int OM>
__global__ __launch_bounds__(256) void gemm_mfma(
    const u16* __restrict__ Ahi, const u16* __restrict__ Alo,
    const u16* __restrict__ Bhi, const u16* __restrict__ Blo,
    float* __restrict__ C, u16* __restrict__ Chi, u16* __restrict__ Clo,
    int K, int M,
    const float* __restrict__ innorm, const float* __restrict__ bias){
  __shared__ u16 sAhi[128*40];
  __shared__ u16 sAlo[128*40];
  __shared__ u16 sBhi[128*40];
  __shared__ u16 sBlo[128*40];
  int tid = threadIdx.x;
  int row0 = blockIdx.x*128, col0 = blockIdx.y*128;
  int wv = tid >> 6, L = tid & 63;
  int wr = (wv >> 1)*64, wc = (wv & 1)*64;
  int srow = tid >> 1, skh = (tid & 1)*16;

  float16v acc[2][2];
  #pragma unroll
  for(int i = 0; i < 2; i++)
    #pragma unroll
    for(int j = 0; j < 2; j++)
      #pragma unroll
      for(int r = 0; r < 16; r++) acc[i][j][r] = 0.f;

  bool av = (row0 + srow) < NN;
  bool bv = (col0 + srow) < M;
  const u16* ahsrc = Ahi + (size_t)(row0 + srow)*K;
  const u16* alsrc = Alo + (size_t)(row0 + srow)*K;
  const u16* bhsrc = Bhi + (size_t)(col0 + srow)*K;
  const u16* blsrc = Blo + (size_t)(col0 + srow)*K;
  const uint4 z4 = make_uint4(0,0,0,0);

  for(int k0 = 0; k0 < K; k0 += 32){
    uint4 ah0 = z4, ah1 = z4, al0 = z4, al1 = z4;
    if(av){
      ah0 = *(const uint4*)&ahsrc[k0 + skh];
      ah1 = *(const uint4*)&ahsrc[k0 + skh + 8];
      al0 = *(const uint4*)&alsrc[k0 + skh];
      al1 = *(const uint4*)&alsrc[k0 + skh + 8];
    }
    uint4 bh0 = z4, bh1 = z4, bl0 = z4, bl1 = z4;
    if(bv){
      bh0 = *(const uint4*)&bhsrc[k0 + skh];
      bh1 = *(const uint4*)&bhsrc[k0 + skh + 8];
      bl0 = *(const uint4*)&blsrc[k0 + skh];
      bl1 = *(const uint4*)&blsrc[k0 + skh + 8];
    }
    __syncthreads();
    int sa = srow*40 + skh;
    *(uint4*)&sAhi[sa]     = ah0;
    *(uint4*)&sAhi[sa + 8] = ah1;
    *(uint4*)&sAlo[sa]     = al0;
    *(uint4*)&sAlo[sa + 8] = al1;
    *(uint4*)&sBhi[sa]     = bh0;
    *(uint4*)&sBhi[sa + 8] = bh1;
    *(uint4*)&sBlo[sa]     = bl0;
    *(uint4*)&sBlo[sa + 8] = bl1;
    __syncthreads();
    #pragma unroll
    for(int ks = 0; ks < 2; ks++){
      int ko = ks*16 + (L >> 5)*8;
      int ra0 = (wr + (L & 31))*40 + ko, ra1 = ra0 + 32*40;
      int rb0 = (wc + (L & 31))*40 + ko, rb1 = rb0 + 32*40;
      short8v ah0v = *(const short8v*)&sAhi[ra0];
      short8v ah1v = *(const short8v*)&sAhi[ra1];
      short8v al0v = *(const short8v*)&sAlo[ra0];
      short8v al1v = *(const short8v*)&sAlo[ra1];
      short8v bhf0 = *(const short8v*)&sBhi[rb0];
      short8v bhf1 = *(const short8v*)&sBhi[rb1];
      short8v blf0 = *(const short8v*)&sBlo[rb0];
      short8v blf1 = *(const short8v*)&sBlo[rb1];
      acc[0][0] = MFMA_BF16(ah0v, bhf0, acc[0][0], 0,0,0);
      acc[0][0] = MFMA_BF16(al0v, bhf0, acc[0][0], 0,0,0);
      acc[0][0] = MFMA_BF16(ah0v, blf0, acc[0][0], 0,0,0);
      acc[0][1] = MFMA_BF16(ah0v, bhf1, acc[0][1], 0,0,0);
      acc[0][1] = MFMA_BF16(al0v, bhf1, acc[0][1], 0,0,0);
      acc[0][1] = MFMA_BF16(ah0v, blf1, acc[0][1], 0,0,0);
      acc[1][0] = MFMA_BF16(ah1v, bhf0, acc[1][0], 0,0,0);
      acc[1][0] = MFMA_BF16(al1v, bhf0, acc[1][0], 0,0,0);
      acc[1][0] = MFMA_BF16(ah1v, blf0, acc[1][0], 0,0,0);
      acc[1][1] = MFMA_BF16(ah1v, bhf1, acc[1][1], 0,0,0);
      acc[1][1] = MFMA_BF16(al1v, bhf1, acc[1][1], 0,0,0);
      acc[1][1] = MFMA_BF16(ah1v, blf1, acc[1][1], 0,0,0);
    }
  }

  int cB = L & 31, rq = 4*(L >> 5);
  #pragma unroll
  for(int tr = 0; tr < 2; tr++){
    #pragma unroll
    for(int tc = 0; tc < 2; tc++){
      int c = col0 + wc + tc*32 + cB;
      if(c >= M) continue;
      #pragma unroll
      for(int reg = 0; reg < 16; reg++){
        int r = row0 + wr + tr*32 + (reg & 3) + 8*(reg >> 2) + rq;
        if(r >= NN) continue;
        float v = acc[tr][tc][reg];
        if(OM == 0){
          C[(size_t)r*M + c] = v;
        } else {
          float t = fmaxf(v*innorm[r] + bias[c], 0.f);
          u16 h = bfhi(t);
          size_t idx = (size_t)r*M + c;
          Chi[idx] = h;
          Clo[idx] = bfhi(t - bf2f(h));
        }
      }
    }
  }
}

// ---------------- predictor v6: MFMA bf16x2-split, 64 pairs/block ------------
// Proven 141-155us; R10-R12 showed three structural rewrites all land 135-168us
// (latency-bound at this occupancy) -> frozen.
#define ZSTR 168
#define P1STR 24
#define Y1STR 88
__global__ __launch_bounds__(256) void predictor_mfma(
    const float* __restrict__ h3,
    const int* __restrict__ ps, const int* __restrict__ pd,
    const int* __restrict__ ns, const int* __restrict__ nd,
    const u16* __restrict__ P1th, const u16* __restrict__ P1tl,
    const float* __restrict__ pb1,
    const u16* __restrict__ P2th, const u16* __restrict__ P2tl,
    const float* __restrict__ pb2,
    const float* __restrict__ P3, const float* __restrict__ pb3,
    float* __restrict__ out){
  __shared__ u16 smem[26112];          // 52224 B
  u16* zh  = smem;                     // [64][168]
  u16* zl  = smem + 64*ZSTR;
  u16* p1h = smem + 2*64*ZSTR;         // [96][24] panel
  u16* p1l = p1h + 96*P1STR;
  u16* y1h = smem;                     // phase B: [64][88]
  u16* y1l = smem + 64*Y1STR;
  u16* p2h = smem + 2*64*Y1STR;        // [64][88]
  u16* p2l = smem + 3*64*Y1STR;
  float* part = (float*)(smem + 4*64*Y1STR);   // [2][64] floats

  int tid = threadIdx.x;
  int pair0 = blockIdx.x*64;           // grid = 400000/64 = 6250 exactly
  int w = tid >> 6, L = tid & 63;
  int lrow = L & 31, lk = (L >> 5)*8;

  // ---- gather z, split to bf16 hi/lo [pair][k] ----
  {
    int p = tid >> 2, sub = tid & 3;
    int q = pair0 + p;
    int a, b;
    if(q < NPAIR){ a = ps[q]; b = pd[q]; }
    else         { a = ns[q-NPAIR]; b = nd[q-NPAIR]; }
    const float4* ra = (const float4*)(h3 + (size_t)a*160);
    const float4* rb = (const float4*)(h3 + (size_t)b*160);
    #pragma unroll
    for(int it = 0; it < 10; it++){
      int g = sub + it*4;
      float4 va = ra[g], vb = rb[g];
      unsigned hp0, lp0, hp1, lp1;
      split2(va.x*vb.x, va.y*vb.y, hp0, lp0);
      split2(va.z*vb.z, va.w*vb.w, hp1, lp1);
      *(uint2*)&zh[p*ZSTR + 4*g] = make_uint2(hp0, hp1);
      *(uint2*)&zl[p*ZSTR + 4*g] = make_uint2(lp0, lp1);
    }
  }

  // ---- stage 1: jobs (pt,ct) = j/3, j%3; wave w -> j1=w, j2=w+4 (w<2) ----
  float16v acc1a, acc1b;
  #pragma unroll
  for(int r = 0; r < 16; r++){ acc1a[r] = 0.f; acc1b[r] = 0.f; }
  int j1 = w, j2 = (w < 2) ? (w + 4) : -1;
  int pt1 = j1/3, ct1 = j1 - pt1*3;
  int pt2 = (j2 >= 0) ? j2/3 : 0;
  int ct2j = (j2 >= 0) ? (j2 - pt2*3) : 0;

  for(int k0 = 0; k0 < 160; k0 += 16){
    __syncthreads();                   // z visible (iter 0) / prev panel reads done
    if(tid < 192){
      int c = tid >> 1, half = tid & 1;
      uint4 vh = *(const uint4*)&P1th[c*160 + k0 + half*8];
      uint4 vl = *(const uint4*)&P1tl[c*160 + k0 + half*8];
      *(uint4*)&p1h[c*P1STR + half*8] = vh;
      *(uint4*)&p1l[c*P1STR + half*8] = vl;
    }
    __syncthreads();
    {
      short8v ah = *(const short8v*)&zh[(pt1*32 + lrow)*ZSTR + k0 + lk];
      short8v al = *(const short8v*)&zl[(pt1*32 + lrow)*ZSTR + k0 + lk];
      short8v bh = *(const short8v*)&p1h[(ct1*32 + lrow)*P1STR + lk];
      short8v bl = *(const short8v*)&p1l[(ct1*32 + lrow)*P1STR + lk];
      acc1a = MFMA_BF16(ah, bh, acc1a, 0,0,0);
      acc1a = MFMA_BF16(al, bh, acc1a, 0,0,0);
      acc1a = MFMA_BF16(ah, bl, acc1a, 0,0,0);
    }
    if(j2 >= 0){
      short8v ah = *(const short8v*)&zh[(pt2*32 + lrow)*ZSTR + k0 + lk];
      short8v al = *(const short8v*)&zl[(pt2*32 + lrow)*ZSTR + k0 + lk];
      short8v bh = *(const short8v*)&p1h[(ct2j*32 + lrow)*P1STR + lk];
      short8v bl = *(const short8v*)&p1l[(ct2j*32 + lrow)*P1STR + lk];
      acc1b = MFMA_BF16(ah, bh, acc1b, 0,0,0);
      acc1b = MFMA_BF16(al, bh, acc1b, 0,0,0);
      acc1b = MFMA_BF16(ah, bl, acc1b, 0,0,0);
    }
  }
  __syncthreads();                     // all z/panel reads done; region reused

  // ---- y1 epilogue (fp32 +pb1, leaky) -> bf16 hi/lo [pair][k=col]; stage P2 --
  {
    int c = ct1*32 + lrow;
    if(c < 80){
      float pb = pb1[c];
      #pragma unroll
      for(int r = 0; r < 16; r++){
        int p = pt1*32 + (r & 3) + 8*(r >> 2) + 4*(L >> 5);
        float v = leaky(acc1a[r] + pb);
        u16 h = bfhi(v);
        y1h[p*Y1STR + c] = h;
        y1l[p*Y1STR + c] = bfhi(v - bf2f(h));
      }
    }
  }
  if(j2 >= 0){
    int c = ct2j*32 + lrow;
    if(c < 80){
      float pb = pb1[c];
      #pragma unroll
      for(int r = 0; r < 16; r++){
        int p = pt2*32 + (r & 3) + 8*(r >> 2) + 4*(L >> 5);
        float v = leaky(acc1b[r] + pb);
        u16 h = bfhi(v);
        y1h[p*Y1STR + c] = h;
        y1l[p*Y1STR + c] = bfhi(v - bf2f(h));
      }
    }
  }
  for(int i = tid; i < 640; i += 256){
    int c = i/10, jj = i - c*10;
    *(uint4*)&p2h[c*Y1STR + jj*8] = *(const uint4*)&P2th[c*80 + jj*8];
    *(uint4*)&p2l[c*Y1STR + jj*8] = *(const uint4*)&P2tl[c*80 + jj*8];
  }
  __syncthreads();

  // ---- stage 2: wave w -> (pt = w&1, c2t = w>>1), K=80 ----
  float16v acc2;
  #pragma unroll
  for(int r = 0; r < 16; r++) acc2[r] = 0.f;
  int pt = w & 1, c2t = w >> 1;
  for(int k0 = 0; k0 < 80; k0 += 16){
    short8v ah = *(const short8v*)&y1h[(pt*32 + lrow)*Y1STR + k0 + lk];
    short8v al = *(const short8v*)&y1l[(pt*32 + lrow)*Y1STR + k0 + lk];
    short8v bh = *(const short8v*)&p2h[(c2t*32 + lrow)*Y1STR + k0 + lk];
    short8v bl = *(const short8v*)&p2l[(c2t*32 + lrow)*Y1STR + k0 + lk];
    acc2 = MFMA_BF16(ah, bh, acc2, 0,0,0);
    acc2 = MFMA_BF16(al, bh, acc2, 0,0,0);
    acc2 = MFMA_BF16(ah, bl, acc2, 0,0,0);
  }

  // ---- stage 3: leaky(+pb2) * P3[c], butterfly-reduce over 32-lane half ----
  int c2 = c2t*32 + lrow;
  float pb2c = (c2 < 40) ? pb2[c2] : 0.f;
  float p3c  = (c2 < 40) ? P3[c2]  : 0.f;
  float vals[16];
  #pragma unroll
  for(int r = 0; r < 16; r++){
    float v = leaky(acc2[r] + pb2c) * p3c;
    #pragma unroll
    for(int m = 1; m < 32; m <<= 1) v += __shfl_xor(v, m);
    vals[r] = v;
  }
  if(lrow == 0){
    #pragma unroll
    for(int r = 0; r < 16; r++){
      int p = pt*32 + (r & 3) + 8*(r >> 2) + 4*(L >> 5);
      part[c2t*64 + p] = vals[r];
    }
  }
  __syncthreads();
  if(tid < 64) out[pair0 + tid] = (part[tid] + part[64 + tid]) + pb3[0];
}

// ---------------- launch ----------------

extern "C" void kernel_launch(void* const* d_in, const int* in_sizes, int n_in,
                              void* d_out, int out_size, void* d_ws, size_t ws_size,
                              hipStream_t stream) {
  const float* x  = (const float*)d_in[0];
  const float* w  = (const float*)d_in[1];
  const int* src  = (const int*)d_in[2];
  const int* dst  = (const int*)d_in[3];
  const int* ps   = (const int*)d_in[4];
  const int* pd   = (const int*)d_in[5];
  const int* ns   = (const int*)d_in[6];
  const int* nd   = (const int*)d_in[7];
  const float* W1 = (const float*)d_in[8];  const float* b1  = (const float*)d_in[9];
  const float* W2 = (const float*)d_in[10]; const float* b2  = (const float*)d_in[11];
  const float* W3 = (const float*)d_in[12]; const float* b3  = (const float*)d_in[13];
  const float* P1 = (const float*)d_in[14]; const float* pb1 = (const float*)d_in[15];
  const float* P2 = (const float*)d_in[16]; const float* pb2 = (const float*)d_in[17];
  const float* P3 = (const float*)d_in[18]; const float* pb3 = (const float*)d_in[19];
  float* out = (float*)d_out;

  char* p = (char*)d_ws;
  auto alloc = [&](size_t bytes)->char*{
    char* r = p; p += (bytes + 255) & ~(size_t)255; return r;
  };
  int*   cnt_out = (int*)  alloc(NN*4);          // these three must stay contiguous
  int*   cnt_in  = (int*)  alloc(NN*4);          // (zeroed with one memset)
  int*   fill    = (int*)  alloc(NN*4);
  int*   row_off = (int*)  alloc((NN+1)*4);
  float* out_nrm = (float*)alloc(NN*4);
  float* in_nrm  = (float*)alloc(NN*4);
  int*   es      = (int*)  alloc((size_t)EE*4);
  float* ew      = (float*)alloc((size_t)EE*4);
  u16*   w1h     = (u16*)  alloc(256*512*2);
  u16*   w1l     = (u16*)  alloc(256*512*2);
  u16*   w2h     = (u16*)  alloc(512*256*2);
  u16*   w2l     = (u16*)  alloc(512*256*2);
  u16*   w3h     = (u16*)  alloc(256*160*2);
  u16*   w3l     = (u16*)  alloc(256*160*2);
  u16*   p1th    = (u16*)  alloc(96*160*2);
  u16*   p1tl    = (u16*)  alloc(96*160*2);
  u16*   p2th    = (u16*)  alloc(64*80*2);
  u16*   p2tl    = (u16*)  alloc(64*80*2);
  u16*   ch      = (u16*)  alloc((size_t)NN*256*2);  // agg1 hi / reused: h2 hi
  u16*   cl      = (u16*)  alloc((size_t)NN*256*2);  // agg1 lo / reused: h2 lo
  u16*   h1h     = (u16*)  alloc((size_t)NN*512*2);  // h1 hi (gemm1 out)
  u16*   h1l     = (u16*)  alloc((size_t)NN*512*2);  // h1 lo
  float* bufB    = (float*)alloc((size_t)NN*256*4);  // proj2 / proj3 (fp32)

  size_t cntPad = (NN*4 + 255) & ~(size_t)255;
  hipMemsetAsync(cnt_out, 0, 3*cntPad, stream);

  degree_kernel<<<(EE+255)/256, 256, 0, stream>>>(src, dst, cnt_out, cnt_in);
  norm_kernel<<<(NN+255)/256, 256, 0, stream>>>(cnt_out, cnt_in, out_nrm, in_nrm);
  scan_kernel<<<1, 512, 0, stream>>>(cnt_in, row_off);
  bucket_kernel<<<(EE+255)/256, 256, 0, stream>>>(src, dst, w, out_nrm, row_off, fill, es, ew);
  wsplit_kernel<<<512, 256, 0, stream>>>(W1, 256, 512, w1h, w1l);
  wsplit_kernel<<<512, 256, 0, stream>>>(W2, 512, 256, w2h, w2l);
  wsplit_kernel<<<160, 256, 0, stream>>>(W3, 256, 160, w3h, w3l);
  psplit_kernel<<<60, 256, 0, stream>>>(P1, P2, p1th, p1tl, p2th, p2tl);

  int aggGrid = (NN + 3)/4;

  // layer 1: agg(x) -> split; gemm1 epilogue relu(*in_norm+b1) -> split h1
  agg_kernel<256,0><<<aggGrid, 256, 0, stream>>>(x, es, ew, row_off, nullptr, nullptr,
                                                 nullptr, ch, cl);
  gemm_mfma<1><<<dim3(391,4), 256, 0, stream>>>(ch, cl, w1h, w1l,
                                                nullptr, h1h, h1l, 256, 512, in_nrm, b1);

  // layer 2: proj2 = h1 @ W2 (fp32); agg2 epilogue relu -> split h2
  gemm_mfma<0><<<dim3(391,2), 256, 0, stream>>>(h1h, h1l, w2h, w2l,
                                                bufB, nullptr, nullptr, 512, 256, nullptr, nullptr);
  agg_kernel<256,1><<<aggGrid, 256, 0, stream>>>(bufB, es, ew, row_off, in_nrm, b2,
                                                 nullptr, ch, cl);

  // layer 3: proj3 = h2 @ W3 (fp32); agg3 -> h3 fp32 in d_out
  gemm_mfma<0><<<dim3(391,2), 256, 0, stream>>>(ch, cl, w3h, w3l,
                                                bufB, nullptr, nullptr, 256, 160, nullptr, nullptr);
  agg_kernel<160,2><<<aggGrid, 256, 0, stream>>>(bufB, es, ew, row_off, in_nrm, b3,
                                                 out + 2*NPAIR, nullptr, nullptr);

  // predictor on pos+neg pairs (v6 verbatim)
  predictor_mfma<<<(2*NPAIR)/64, 256, 0, stream>>>(out + 2*NPAIR, ps, pd, ns, nd,
                                                   p1th, p1tl, pb1, p2th, p2tl, pb2,
                                                   P3, pb3, out);
}

// Round 6
// 902.290 us; speedup vs baseline: 1.0506x; 1.0506x over previous
//
#include <hip/hip_runtime.h>
#include <math.h>

#define NN 50000
#define NNP 50048          // NN padded to 128 (GEMM row blocks read pad rows)
#define EE 800000
#define NPAIR 200000

typedef unsigned short u16;
typedef short short8v __attribute__((ext_vector_type(8)));
typedef float float16v __attribute__((ext_vector_type(16)));

__device__ __forceinline__ float leaky(float x){ return x >= 0.f ? x : 0.2f*x; }

// bf16 round-to-nearest-even helpers for the hi/lo split
__device__ __forceinline__ u16 bfhi(float x){
  union{float f; unsigned u;} v; v.f = x;
  unsigned r = (v.u + 0x7FFFu + ((v.u >> 16) & 1u)) >> 16;
  return (u16)r;
}
__device__ __forceinline__ float bf2f(u16 h){
  union{unsigned u; float f;} v; v.u = ((unsigned)h) << 16; return v.f;
}
__device__ __forceinline__ void split2(float x, float y, unsigned &hp, unsigned &lp){
  u16 hx = bfhi(x), hy = bfhi(y);
  u16 lx = bfhi(x - bf2f(hx)), ly = bfhi(y - bf2f(hy));
  hp = (unsigned)hx | ((unsigned)hy << 16);
  lp = (unsigned)lx | ((unsigned)ly << 16);
}
#define MFMA_BF16 __builtin_amdgcn_mfma_f32_32x32x16_bf16

// async global->LDS, 16B per lane. LDS dest = wave-uniform base + lane*16;
// global src is per-lane (guide m97/m104).
__device__ __forceinline__ void gload16(const u16* g, u16* l){
  __builtin_amdgcn_global_load_lds(
      (const __attribute__((address_space(1))) unsigned int*)(g),
      (__attribute__((address_space(3))) unsigned int*)(l), 16, 0, 0);
}

// ---------------- PS layout (R15) -------------------------------------------
// Packed-split bf16 matrix: for row r, K-block kb (32 cols), 64 u16:
//   logical j: 0..31 = hi of col kb*32+j, 32..63 = lo of col kb*32+(j-32)
//   stored 16B-chunk-swizzled: chunk c = j>>3 goes to slot c ^ (r&7).
// Producers write swizzled; GEMM stages LINEAR via global_load_lds (can't
// swizzle its dest, m104); ds_read applies the same XOR (m201 pattern).
// Bank math: frag read = 32 lanes rows r..r+31, slot (c^(L&7)) -> 8 slots x 4
// banks = 32 banks, 4-way alias — identical to the old pad-40 layout, but the
// VGPR round-trip + ds_write are gone (the m93->m97 +67% lever).

// ---------------- degree / norms / CSR build ----------------

__global__ void degree_kernel(const int* __restrict__ src, const int* __restrict__ dst,
                              int* cnt_out, int* cnt_in){
  int i = blockIdx.x*blockDim.x + threadIdx.x;
  if(i < EE){
    atomicAdd(&cnt_out[src[i]], 1);
    atomicAdd(&cnt_in[dst[i]], 1);
  }
}

__global__ void norm_kernel(const int* __restrict__ cnt_out, const int* __restrict__ cnt_in,
                            float* __restrict__ out_norm, float* __restrict__ in_norm){
  int i = blockIdx.x*blockDim.x + threadIdx.x;
  if(i < NN){
    int o = cnt_out[i]; if(o < 1) o = 1;
    int d = cnt_in[i];  if(d < 1) d = 1;
    out_norm[i] = 1.f/sqrtf((float)o);
    in_norm[i]  = 1.f/sqrtf((float)d);
  }
}

// single-block exclusive scan of cnt_in[NN] -> row_off[NN+1]
// R15: 1024 threads + int4 sums (old: 512 thr x 98 scalar loads, serial-ish).
__global__ void scan_kernel(const int* __restrict__ cnt, int* __restrict__ row_off){
  const int T = 1024;
  const int CH = 52;                  // 1024*52 = 53248 >= NN, multiple of 4
  __shared__ int sums[T];
  int t = threadIdx.x;
  int base = t*CH;
  int hi = base + CH; if(hi > NN) hi = NN;
  int s = 0;
  if(base < NN){
    int i = base;
    for(; i + 3 < hi; i += 4){
      int4 v = *(const int4*)&cnt[i];
      s += (v.x + v.y) + (v.z + v.w);
    }
    for(; i < hi; i++) s += cnt[i];
  }
  sums[t] = s;
  __syncthreads();
  for(int off = 1; off < T; off <<= 1){
    int add = (t >= off) ? sums[t-off] : 0;
    __syncthreads();
    sums[t] += add;
    __syncthreads();
  }
  int run = sums[t] - s;
  if(base < NN){
    for(int i = base; i < hi; i++){ row_off[i] = run; run += cnt[i]; }
  }
  if(t == T-1) row_off[NN] = EE;
}

// ew2 = w * out_norm[src]: out_norm commutes with @W, folded into edge weight.
__global__ void bucket_kernel(const int* __restrict__ src, const int* __restrict__ dst,
                              const float* __restrict__ w, const float* __restrict__ out_norm,
                              const int* __restrict__ row_off,
                              int* fill, int* __restrict__ es, float* __restrict__ ew){
  int i = blockIdx.x*blockDim.x + threadIdx.x;
  if(i < EE){
    int d = dst[i];
    int s = src[i];
    int p = row_off[d] + atomicAdd(&fill[d], 1);
    es[p] = s;
    ew[p] = w[i] * out_norm[s];
  }
}

// W (K x M fp32, row-major) -> PS layout (M rows, K cols, swizzled).
__global__ void wsplit_kernel(const float* __restrict__ W, int K, int M,
                              u16* __restrict__ PS){
  int i = blockIdx.x*256 + threadIdx.x;     // i = m*K + k
  if(i < K*M){
    int m = i / K, k = i - m*K;
    float a = W[(size_t)k*M + m];
    u16 h = bfhi(a);
    u16 lo = bfhi(a - bf2f(h));
    int kb = k >> 5, j = k & 31, c = j >> 3, swz = m & 7;
    size_t base = ((size_t)m*(K >> 5) + kb)*64 + (j & 7);
    PS[base + ((c    ) ^ swz)*8] = h;
    PS[base + ((c + 4) ^ swz)*8] = lo;
  }
}

// P1 (160x80) -> P1t hi/lo [96 cols][160 k] (cols 80..95 zero);
// P2 (80x40)  -> P2t hi/lo [64 cols][80 k]  (cols 40..63 zero).
// (predictor keeps its own proven layouts — untouched)
__global__ void psplit_kernel(const float* __restrict__ P1, const float* __restrict__ P2,
                              u16* __restrict__ P1th, u16* __restrict__ P1tl,
                              u16* __restrict__ P2th, u16* __restrict__ P2tl){
  int i = blockIdx.x*256 + threadIdx.x;
  if(i < 96*160){
    int c = i/160, k = i - c*160;
    float v = (c < 80) ? P1[k*80 + c] : 0.f;
    u16 h = bfhi(v);
    P1th[i] = h; P1tl[i] = bfhi(v - bf2f(h));
  }
  if(i < 64*80){
    int c = i/80, k = i - c*80;
    float v = (c < 40) ? P2[k*40 + c] : 0.f;
    u16 h = bfhi(v);
    P2th[i] = h; P2tl[i] = bfhi(v - bf2f(h));
  }
}

// ---------------- aggregation: one WAVE per node, 8-deep, PS output ----------
// MODE 0: raw agg -> PS (feeds GEMM A). MODE 1: relu(*innorm+bias) -> PS.
// MODE 2: *innorm+bias -> fp32 (h3; predictor gathers fp32).
template<int F, int MODE>
__global__ __launch_bounds__(256) void agg_kernel(
    const float* __restrict__ feat, const int* __restrict__ es,
    const float* __restrict__ ew, const int* __restrict__ row_off,
    const float* __restrict__ innorm, const float* __restrict__ bias,
    float* __restrict__ out_f, u16* __restrict__ out_ps){
  constexpr int F4 = F/4;
  int wid = threadIdx.x >> 6, lane = threadIdx.x & 63;
  int v = blockIdx.x*4 + wid;
  if(v >= NN || lane >= F4) return;
  int s = row_off[v], e = row_off[v+1];
  const float4* f4 = (const float4*)feat;
  float4 a0 = {0,0,0,0}, a1 = {0,0,0,0}, a2 = {0,0,0,0}, a3 = {0,0,0,0};
  int j = s;
  for(; j + 7 < e; j += 8){
    int   i0 = es[j],   i1 = es[j+1], i2 = es[j+2], i3 = es[j+3];
    int   i4 = es[j+4], i5 = es[j+5], i6 = es[j+6], i7 = es[j+7];
    float w0 = ew[j],   w1 = ew[j+1], w2 = ew[j+2], w3 = ew[j+3];
    float w4 = ew[j+4], w5 = ew[j+5], w6 = ew[j+6], w7 = ew[j+7];
    float4 r0 = f4[(size_t)i0*F4 + lane];
    float4 r1 = f4[(size_t)i1*F4 + lane];
    float4 r2 = f4[(size_t)i2*F4 + lane];
    float4 r3 = f4[(size_t)i3*F4 + lane];
    float4 r4 = f4[(size_t)i4*F4 + lane];
    float4 r5 = f4[(size_t)i5*F4 + lane];
    float4 r6 = f4[(size_t)i6*F4 + lane];
    float4 r7 = f4[(size_t)i7*F4 + lane];
    a0.x += r0.x*w0; a0.y += r0.y*w0; a0.z += r0.z*w0; a0.w += r0.w*w0;
    a1.x += r1.x*w1; a1.y += r1.y*w1; a1.z += r1.z*w1; a1.w += r1.w*w1;
    a2.x += r2.x*w2; a2.y += r2.y*w2; a2.z += r2.z*w2; a2.w += r2.w*w2;
    a3.x += r3.x*w3; a3.y += r3.y*w3; a3.z += r3.z*w3; a3.w += r3.w*w3;
    a0.x += r4.x*w4; a0.y += r4.y*w4; a0.z += r4.z*w4; a0.w += r4.w*w4;
    a1.x += r5.x*w5; a1.y += r5.y*w5; a1.z += r5.z*w5; a1.w += r5.w*w5;
    a2.x += r6.x*w6; a2.y += r6.y*w6; a2.z += r6.z*w6; a2.w += r6.w*w6;
    a3.x += r7.x*w7; a3.y += r7.y*w7; a3.z += r7.z*w7; a3.w += r7.w*w7;
  }
  for(; j + 3 < e; j += 4){
    int   i0 = es[j],   i1 = es[j+1], i2 = es[j+2], i3 = es[j+3];
    float w0 = ew[j],   w1 = ew[j+1], w2 = ew[j+2], w3 = ew[j+3];
    float4 r0 = f4[(size_t)i0*F4 + lane];
    float4 r1 = f4[(size_t)i1*F4 + lane];
    float4 r2 = f4[(size_t)i2*F4 + lane];
    float4 r3 = f4[(size_t)i3*F4 + lane];
    a0.x += r0.x*w0; a0.y += r0.y*w0; a0.z += r0.z*w0; a0.w += r0.w*w0;
    a1.x += r1.x*w1; a1.y += r1.y*w1; a1.z += r1.z*w1; a1.w += r1.w*w1;
    a2.x += r2.x*w2; a2.y += r2.y*w2; a2.z += r2.z*w2; a2.w += r2.w*w2;
    a3.x += r3.x*w3; a3.y += r3.y*w3; a3.z += r3.z*w3; a3.w += r3.w*w3;
  }
  for(; j < e; j++){
    int idx = es[j]; float wt = ew[j];
    float4 r = f4[(size_t)idx*F4 + lane];
    a0.x += r.x*wt; a0.y += r.y*wt; a0.z += r.z*wt; a0.w += r.w*wt;
  }
  float4 r;
  r.x = (a0.x+a1.x)+(a2.x+a3.x);
  r.y = (a0.y+a1.y)+(a2.y+a3.y);
  r.z = (a0.z+a1.z)+(a2.z+a3.z);
  r.w = (a0.w+a1.w)+(a2.w+a3.w);
  if(MODE >= 1){
    float inm = innorm[v];
    float4 bb = *(const float4*)&bias[lane*4];
    r.x = r.x*inm + bb.x; r.y = r.y*inm + bb.y;
    r.z = r.z*inm + bb.z; r.w = r.w*inm + bb.w;
    if(MODE == 1){
      r.x = fmaxf(r.x, 0.f); r.y = fmaxf(r.y, 0.f);
      r.z = fmaxf(r.z, 0.f); r.w = fmaxf(r.w, 0.f);
    }
  }
  if(MODE == 2){
    ((float4*)(out_f + (size_t)v*F))[lane] = r;
  } else {
    // lane covers cols 4L..4L+3: kb = L>>3, hi chunk = (L>>1)&3, j&7 = (L&1)*4
    unsigned hp0, lp0, hp1, lp1;
    split2(r.x, r.y, hp0, lp0);
    split2(r.z, r.w, hp1, lp1);
    int kb = lane >> 3, ch = (lane >> 1) & 3, swz = v & 7, off = (lane & 1)*4;
    u16* row = out_ps + ((size_t)v*(F >> 5) + kb)*64;
    *(uint2*)&row[((ch    ) ^ swz)*8 + off] = make_uint2(hp0, hp1);
    *(uint2*)&row[((ch + 4) ^ swz)*8 + off] = make_uint2(lp0, lp1);
  }
}

// ---------------- GEMM v3: global_load_lds staging + PS operands (R15) -------
// 2-barrier K-loop, but staging is 8x 16B global_load_lds per thread per
// K-step: no VGPR round trip, no ds_write. LDS 32KB -> 5 blocks/CU.
// OM 0: write fp32 C. OM 1: relu(*innorm+bias) -> PS (h1, feeds gemm2's A).
template<int OM>
__global__ __launch_bounds__(256) void gemm_mfma(
    const u16* __restrict__ APS, const u16* __restrict__ BPS,
    float* __restrict__ C, u16* __restrict__ CPS,
    int K, int M,
    const float* __restrict__ innorm, const float* __restrict__ bias){
  __shared__ u16 sA[8192];     // [128 rows][64 u16], chunk-swizzled content
  __shared__ u16 sB[8192];
  int tid = threadIdx.x;
  int row0 = blockIdx.x*128, col0 = blockIdx.y*128;
  int wv = tid >> 6, L = tid & 63;
  int wr = (wv >> 1)*64, wc = (wv & 1)*64;
  int KB = K >> 5;

  float16v acc[2][2];
  #pragma unroll
  for(int i = 0; i < 2; i++)
    #pragma unroll
    for(int j = 0; j < 2; j++)
      #pragma unroll
      for(int r = 0; r < 16; r++) acc[i][j][r] = 0.f;

  const u16* abase = APS + (size_t)row0*KB*64;
  const u16* bbase = BPS + (size_t)col0*KB*64;
  int lr8 = L >> 3, lc8 = (L & 7)*8;

  for(int kblk = 0; kblk < KB; kblk++){
    __syncthreads();                       // prev K-step's reads done
    #pragma unroll
    for(int i = 0; i < 4; i++){
      int rb = wv*32 + i*8;                // 8 rows x 128B = 1KB per issue
      gload16(abase + ((size_t)(rb + lr8)*KB + kblk)*64 + lc8, &sA[rb*64]);
      gload16(bbase + ((size_t)(rb + lr8)*KB + kblk)*64 + lc8, &sB[rb*64]);
    }
    __syncthreads();                       // drains vmcnt -> tiles visible
    #pragma unroll
    for(int ks = 0; ks < 2; ks++){
      int swz = L & 7;                     // == (row&7) for all rows read
      int ch = ks*2 + (L >> 5);
      int oh = ((ch    ) ^ swz)*8;
      int ol = ((ch + 4) ^ swz)*8;
      int r0 = (wr + (L & 31))*64, r1 = r0 + 32*64;
      int q0 = (wc + (L & 31))*64, q1 = q0 + 32*64;
      short8v ah0 = *(const short8v*)&sA[r0 + oh];
      short8v al0 = *(const short8v*)&sA[r0 + ol];
      short8v ah1 = *(const short8v*)&sA[r1 + oh];
      short8v al1 = *(const short8v*)&sA[r1 + ol];
      short8v bh0 = *(const short8v*)&sB[q0 + oh];
      short8v bl0 = *(const short8v*)&sB[q0 + ol];
      short8v bh1 = *(const short8v*)&sB[q1 + oh];
      short8v bl1 = *(const short8v*)&sB[q1 + ol];
      acc[0][0] = MFMA_BF16(ah0, bh0, acc[0][0], 0,0,0);
      acc[0][0] = MFMA_BF16(al0, bh0, acc[0][0], 0,0,0);
      acc[0][0] = MFMA_BF16(ah0, bl0, acc[0][0], 0,0,0);
      acc[0][1] = MFMA_BF16(ah0, bh1, acc[0][1], 0,0,0);
      acc[0][1] = MFMA_BF16(al0, bh1, acc[0][1], 0,0,0);
      acc[0][1] = MFMA_BF16(ah0, bl1, acc[0][1], 0,0,0);
      acc[1][0] = MFMA_BF16(ah1, bh0, acc[1][0], 0,0,0);
      acc[1][0] = MFMA_BF16(al1, bh0, acc[1][0], 0,0,0);
      acc[1][0] = MFMA_BF16(ah1, bl0, acc[1][0], 0,0,0);
      acc[1][1] = MFMA_BF16(ah1, bh1, acc[1][1], 0,0,0);
      acc[1][1] = MFMA_BF16(al1, bh1, acc[1][1], 0,0,0);
      acc[1][1] = MFMA_BF16(ah1, bl1, acc[1][1], 0,0,0);
    }
  }

  int cB = L & 31, rq = 4*(L >> 5);
  #pragma unroll
  for(int tr = 0; tr < 2; tr++){
    #pragma unroll
    for(int tc = 0; tc < 2; tc++){
      int c = col0 + wc + tc*32 + cB;
      if(c >= M) continue;
      #pragma unroll
      for(int reg = 0; reg < 16; reg++){
        int r = row0 + wr + tr*32 + (reg & 3) + 8*(reg >> 2) + rq;
        if(r >= NN) continue;
        float v = acc[tr][tc][reg];
        if(OM == 0){
          C[(size_t)r*M + c] = v;
        } else {
          float t = fmaxf(v*innorm[r] + bias[c], 0.f);
          u16 h = bfhi(t);
          u16 lo = bfhi(t - bf2f(h));
          int kb = c >> 5, jj = c & 31, cc = jj >> 3, swz = r & 7;
          size_t base = ((size_t)r*(M >> 5) + kb)*64 + (jj & 7);
          CPS[base + ((cc    ) ^ swz)*8] = h;
          CPS[base + ((cc + 4) ^ swz)*8] = lo;
        }
      }
    }
  }
}

// ---------------- predictor v6: MFMA bf16x2-split, 64 pairs/block ------------
// Proven 141-155us; R10-R12: three structural rewrites all land 135-168us
// (gather-latency-bound at this occupancy) -> frozen.
#define ZSTR 168
#define P1STR 24
#define Y1STR 88
__global__ __launch_bounds__(256) void predictor_mfma(
    const float* __restrict__ h3,
    const int* __restrict__ ps, const int* __restrict__ pd,
    const int* __restrict__ ns, const int* __restrict__ nd,
    const u16* __restrict__ P1th, const u16* __restrict__ P1tl,
    const float* __restrict__ pb1,
    const u16* __restrict__ P2th, const u16* __restrict__ P2tl,
    const float* __restrict__ pb2,
    const float* __restrict__ P3, const float* __restrict__ pb3,
    float* __restrict__ out){
  __shared__ u16 smem[26112];          // 52224 B
  u16* zh  = smem;                     // [64][168]
  u16* zl  = smem + 64*ZSTR;
  u16* p1h = smem + 2*64*ZSTR;         // [96][24] panel
  u16* p1l = p1h + 96*P1STR;
  u16* y1h = smem;                     // phase B: [64][88]
  u16* y1l = smem + 64*Y1STR;
  u16* p2h = smem + 2*64*Y1STR;        // [64][88]
  u16* p2l = smem + 3*64*Y1STR;
  float* part = (float*)(smem + 4*64*Y1STR);   // [2][64] floats

  int tid = threadIdx.x;
  int pair0 = blockIdx.x*64;           // grid = 400000/64 = 6250 exactly
  int w = tid >> 6, L = tid & 63;
  int lrow = L & 31, lk = (L >> 5)*8;

  // ---- gather z, split to bf16 hi/lo [pair][k] ----
  {
    int p = tid >> 2, sub = tid & 3;
    int q = pair0 + p;
    int a, b;
    if(q < NPAIR){ a = ps[q]; b = pd[q]; }
    else         { a = ns[q-NPAIR]; b = nd[q-NPAIR]; }
    const float4* ra = (const float4*)(h3 + (size_t)a*160);
    const float4* rb = (const float4*)(h3 + (size_t)b*160);
    #pragma unroll
    for(int it = 0; it < 10; it++){
      int g = sub + it*4;
      float4 va = ra[g], vb = rb[g];
      unsigned hp0, lp0, hp1, lp1;
      split2(va.x*vb.x, va.y*vb.y, hp0, lp0);
      split2(va.z*vb.z, va.w*vb.w, hp1, lp1);
      *(uint2*)&zh[p*ZSTR + 4*g] = make_uint2(hp0, hp1);
      *(uint2*)&zl[p*ZSTR + 4*g] = make_uint2(lp0, lp1);
    }
  }

  // ---- stage 1: jobs (pt,ct) = j/3, j%3; wave w -> j1=w, j2=w+4 (w<2) ----
  float16v acc1a, acc1b;
  #pragma unroll
  for(int r = 0; r < 16; r++){ acc1a[r] = 0.f; acc1b[r] = 0.f; }
  int j1 = w, j2 = (w < 2) ? (w + 4) : -1;
  int pt1 = j1/3, ct1 = j1 - pt1*3;
  int pt2 = (j2 >= 0) ? j2/3 : 0;
  int ct2j = (j2 >= 0) ? (j2 - pt2*3) : 0;

  for(int k0 = 0; k0 < 160; k0 += 16){
    __syncthreads();                   // z visible (iter 0) / prev panel reads done
    if(tid < 192){
      int c = tid >> 1, half = tid & 1;
      uint4 vh = *(const uint4*)&P1th[c*160 + k0 + half*8];
      uint4 vl = *(const uint4*)&P1tl[c*160 + k0 + half*8];
      *(uint4*)&p1h[c*P1STR + half*8] = vh;
      *(uint4*)&p1l[c*P1STR + half*8] = vl;
    }
    __syncthreads();
    {
      short8v ah = *(const short8v*)&zh[(pt1*32 + lrow)*ZSTR + k0 + lk];
      short8v al = *(const short8v*)&zl[(pt1*32 + lrow)*ZSTR + k0 + lk];
      short8v bh = *(const short8v*)&p1h[(ct1*32 + lrow)*P1STR + lk];
      short8v bl = *(const short8v*)&p1l[(ct1*32 + lrow)*P1STR + lk];
      acc1a = MFMA_BF16(ah, bh, acc1a, 0,0,0);
      acc1a = MFMA_BF16(al, bh, acc1a, 0,0,0);
      acc1a = MFMA_BF16(ah, bl, acc1a, 0,0,0);
    }
    if(j2 >= 0){
      short8v ah = *(const short8v*)&zh[(pt2*32 + lrow)*ZSTR + k0 + lk];
      short8v al = *(const short8v*)&zl[(pt2*32 + lrow)*ZSTR + k0 + lk];
      short8v bh = *(const short8v*)&p1h[(ct2j*32 + lrow)*P1STR + lk];
      short8v bl = *(const short8v*)&p1l[(ct2j*32 + lrow)*P1STR + lk];
      acc1b = MFMA_BF16(ah, bh, acc1b, 0,0,0);
      acc1b = MFMA_BF16(al, bh, acc1b, 0,0,0);
      acc1b = MFMA_BF16(ah, bl, acc1b, 0,0,0);
    }
  }
  __syncthreads();                     // all z/panel reads done; region reused

  // ---- y1 epilogue (fp32 +pb1, leaky) -> bf16 hi/lo [pair][k=col]; stage P2 --
  {
    int c = ct1*32 + lrow;
    if(c < 80){
      float pb = pb1[c];
      #pragma unroll
      for(int r = 0; r < 16; r++){
        int p = pt1*32 + (r & 3) + 8*(r >> 2) + 4*(L >> 5);
        float v = leaky(acc1a[r] + pb);
        u16 h = bfhi(v);
        y1h[p*Y1STR + c] = h;
        y1l[p*Y1STR + c] = bfhi(v - bf2f(h));
      }
    }
  }
  if(j2 >= 0){
    int c = ct2j*32 + lrow;
    if(c < 80){
      float pb = pb1[c];
      #pragma unroll
      for(int r = 0; r < 16; r++){
        int p = pt2*32 + (r & 3) + 8*(r >> 2) + 4*(L >> 5);
        float v = leaky(acc1b[r] + pb);
        u16 h = bfhi(v);
        y1h[p*Y1STR + c] = h;
        y1l[p*Y1STR + c] = bfhi(v - bf2f(h));
      }
    }
  }
  for(int i = tid; i < 640; i += 256){
    int c = i/10, jj = i - c*10;
    *(uint4*)&p2h[c*Y1STR + jj*8] = *(const uint4*)&P2th[c*80 + jj*8];
    *(uint4*)&p2l[c*Y1STR + jj*8] = *(const uint4*)&P2tl[c*80 + jj*8];
  }
  __syncthreads();

  // ---- stage 2: wave w -> (pt = w&1, c2t = w>>1), K=80 ----
  float16v acc2;
  #pragma unroll
  for(int r = 0; r < 16; r++) acc2[r] = 0.f;
  int pt = w & 1, c2t = w >> 1;
  for(int k0 = 0; k0 < 80; k0 += 16){
    short8v ah = *(const short8v*)&y1h[(pt*32 + lrow)*Y1STR + k0 + lk];
    short8v al = *(const short8v*)&y1l[(pt*32 + lrow)*Y1STR + k0 + lk];
    short8v bh = *(const short8v*)&p2h[(c2t*32 + lrow)*Y1STR + k0 + lk];
    short8v bl = *(const short8v*)&p2l[(c2t*32 + lrow)*Y1STR + k0 + lk];
    acc2 = MFMA_BF16(ah, bh, acc2, 0,0,0);
    acc2 = MFMA_BF16(al, bh, acc2, 0,0,0);
    acc2 = MFMA_BF16(ah, bl, acc2, 0,0,0);
  }

  // ---- stage 3: leaky(+pb2) * P3[c], butterfly-reduce over 32-lane half ----
  int c2 = c2t*32 + lrow;
  float pb2c = (c2 < 40) ? pb2[c2] : 0.f;
  float p3c  = (c2 < 40) ? P3[c2]  : 0.f;
  float vals[16];
  #pragma unroll
  for(int r = 0; r < 16; r++){
    float v = leaky(acc2[r] + pb2c) * p3c;
    #pragma unroll
    for(int m = 1; m < 32; m <<= 1) v += __shfl_xor(v, m);
    vals[r] = v;
  }
  if(lrow == 0){
    #pragma unroll
    for(int r = 0; r < 16; r++){
      int p = pt*32 + (r & 3) + 8*(r >> 2) + 4*(L >> 5);
      part[c2t*64 + p] = vals[r];
    }
  }
  __syncthreads();
  if(tid < 64) out[pair0 + tid] = (part[tid] + part[64 + tid]) + pb3[0];
}

// ---------------- launch ----------------

extern "C" void kernel_launch(void* const* d_in, const int* in_sizes, int n_in,
                              void* d_out, int out_size, void* d_ws, size_t ws_size,
                              hipStream_t stream) {
  const float* x  = (const float*)d_in[0];
  const float* w  = (const float*)d_in[1];
  const int* src  = (const int*)d_in[2];
  const int* dst  = (const int*)d_in[3];
  const int* ps   = (const int*)d_in[4];
  const int* pd   = (const int*)d_in[5];
  const int* ns   = (const int*)d_in[6];
  const int* nd   = (const int*)d_in[7];
  const float* W1 = (const float*)d_in[8];  const float* b1  = (const float*)d_in[9];
  const float* W2 = (const float*)d_in[10]; const float* b2  = (const float*)d_in[11];
  const float* W3 = (const float*)d_in[12]; const float* b3  = (const float*)d_in[13];
  const float* P1 = (const float*)d_in[14]; const float* pb1 = (const float*)d_in[15];
  const float* P2 = (const float*)d_in[16]; const float* pb2 = (const float*)d_in[17];
  const float* P3 = (const float*)d_in[18]; const float* pb3 = (const float*)d_in[19];
  float* out = (float*)d_out;

  char* p = (char*)d_ws;
  auto alloc = [&](size_t bytes)->char*{
    char* r = p; p += (bytes + 255) & ~(size_t)255; return r;
  };
  int*   cnt_out = (int*)  alloc(NN*4);          // these three must stay contiguous
  int*   cnt_in  = (int*)  alloc(NN*4);          // (zeroed with one memset)
  int*   fill    = (int*)  alloc(NN*4);
  int*   row_off = (int*)  alloc((NN+1)*4);
  float* out_nrm = (float*)alloc(NN*4);
  float* in_nrm  = (float*)alloc(NN*4);
  int*   es      = (int*)  alloc((size_t)EE*4);
  float* ew      = (float*)alloc((size_t)EE*4);
  u16*   w1PS    = (u16*)  alloc((size_t)512*512*2);    // M=512 rows, K=256
  u16*   w2PS    = (u16*)  alloc((size_t)256*1024*2);   // M=256 rows, K=512
  u16*   w3PS    = (u16*)  alloc((size_t)256*512*2);    // M=160->256 pad, K=256
  u16*   p1th    = (u16*)  alloc(96*160*2);
  u16*   p1tl    = (u16*)  alloc(96*160*2);
  u16*   p2th    = (u16*)  alloc(64*80*2);
  u16*   p2tl    = (u16*)  alloc(64*80*2);
  u16*   aggPS   = (u16*)  alloc((size_t)NNP*512*2);    // agg1 / h2 (K=256 PS)
  u16*   h1PS    = (u16*)  alloc((size_t)NNP*1024*2);   // h1 (K=512 PS)
  float* bufB    = (float*)alloc((size_t)NN*256*4);     // proj2 / proj3 (fp32)

  size_t cntPad = (NN*4 + 255) & ~(size_t)255;
  hipMemsetAsync(cnt_out, 0, 3*cntPad, stream);

  degree_kernel<<<(EE+255)/256, 256, 0, stream>>>(src, dst, cnt_out, cnt_in);
  norm_kernel<<<(NN+255)/256, 256, 0, stream>>>(cnt_out, cnt_in, out_nrm, in_nrm);
  scan_kernel<<<1, 1024, 0, stream>>>(cnt_in, row_off);
  bucket_kernel<<<(EE+255)/256, 256, 0, stream>>>(src, dst, w, out_nrm, row_off, fill, es, ew);
  wsplit_kernel<<<512, 256, 0, stream>>>(W1, 256, 512, w1PS);
  wsplit_kernel<<<512, 256, 0, stream>>>(W2, 512, 256, w2PS);
  wsplit_kernel<<<160, 256, 0, stream>>>(W3, 256, 160, w3PS);
  psplit_kernel<<<60, 256, 0, stream>>>(P1, P2, p1th, p1tl, p2th, p2tl);

  int aggGrid = (NN + 3)/4;

  // layer 1: agg(x) -> PS; gemm1 epilogue relu(*in_norm+b1) -> h1 PS
  agg_kernel<256,0><<<aggGrid, 256, 0, stream>>>(x, es, ew, row_off, nullptr, nullptr,
                                                 nullptr, aggPS);
  gemm_mfma<1><<<dim3(391,4), 256, 0, stream>>>(aggPS, w1PS, nullptr, h1PS,
                                                256, 512, in_nrm, b1);

  // layer 2: proj2 = h1 @ W2 (fp32); agg2 epilogue relu -> PS (h2)
  gemm_mfma<0><<<dim3(391,2), 256, 0, stream>>>(h1PS, w2PS, bufB, nullptr,
                                                512, 256, nullptr, nullptr);
  agg_kernel<256,1><<<aggGrid, 256, 0, stream>>>(bufB, es, ew, row_off, in_nrm, b2,
                                                 nullptr, aggPS);

  // layer 3: proj3 = h2 @ W3 (fp32); agg3 -> h3 fp32 in d_out
  gemm_mfma<0><<<dim3(391,2), 256, 0, stream>>>(aggPS, w3PS, bufB, nullptr,
                                                256, 160, nullptr, nullptr);
  agg_kernel<160,2><<<aggGrid, 256, 0, stream>>>(bufB, es, ew, row_off, in_nrm, b3,
                                                 out + 2*NPAIR, nullptr);

  // predictor on pos+neg pairs (v6 verbatim)
  predictor_mfma<<<(2*NPAIR)/64, 256, 0, stream>>>(out + 2*NPAIR, ps, pd, ns, nd,
                                                   p1th, p1tl, pb1, p2th, p2tl, pb2,
                                                   P3, pb3, out);
}